// Round 13
// baseline (23.225 us; speedup 1.0000x reference)
//
#include <hip/hip_runtime.h>
#include <hip/hip_fp16.h>

// Kuramoto closed-loop — bit-pack streamer + tiny compute.
//
//  s_int[j] = cj*x2j*(A c)j + sj*x2j*(A s)j - cj*(A (c*x2))j - sj*(A (s*x2))j
//  u        = -(A v);  gterm = G2d/n * (A x2)
//  gamma   ~= 0.85 * mean_{8 rows of block}(sw_i * deg_i^2)  (Rayleigh sample)
//
// Lessons ledger:
//  r1/r3/r4: register tables spill -> WRITE_SIZE is the spill alarm.
//  r5:  prefetch distance must match buffer count.
//  r6:  split tabE/tabO arrays -> conflict-free b128 (655K -> 0).
//  r7:  builtins return __fp16 vectors -> decltype the builtin.
//  r8:  redundant per-block table build dominated VALU -> prep once.
//  r9-r12: 20-25us plateau across 3 compute engines -> the wall is the 64MB
//       zero-reuse fp32 stream at ~4 TB/s effective (68% of m13 ceiling).
//  r13(this): adjacency is 0/1 -> bit-pack it. k_pack = PURE streamer
//       (64MB -> 2MB nibble words; prep folded into blocks 0-3, hidden).
//       k_main consumes 2 uint32/lane instead of 16 float4; deg = popcount.
//       Pack layout matches r12's table access exactly (no swizzle change).

#define NN 4096
#define KCOUPLING 3.0f
#define ROWS 8

typedef decltype(__builtin_amdgcn_cvt_pkrtz(0.0f, 0.0f)) h2_t;  // __fp16 x2
typedef float f4_t __attribute__((ext_vector_type(4)));

__device__ __forceinline__ unsigned pk2rn_u(float a, float b) {  // RN table
  __half2 h = __floats2half2_rn(a, b);
  return *reinterpret_cast<unsigned*>(&h);
}
__device__ __forceinline__ float fdot2(h2_t a, h2_t b, float c) {
#if __has_builtin(__builtin_amdgcn_fdot2)
  return __builtin_amdgcn_fdot2(a, b, c, false);
#else
  return fmaf((float)a.x, (float)b.x, fmaf((float)a.y, (float)b.y, c));
#endif
}
__device__ __forceinline__ h2_t bch2(unsigned u) {
  union { unsigned u; h2_t h; } x; x.u = u; return x.h;
}

// ---- pack: pure streamer. wave W = (row, half); lane handles 8 f4 groups
// {h*512 + s*64 + lane}; nibble s of its word = that f4's !=0 bits.
// Blocks 0..3 additionally build the f16 col table (hidden under the stream).
__global__ __launch_bounds__(256) void k_pack(
    const f4_t* __restrict__ adj4, unsigned* __restrict__ words,
    const float* __restrict__ x, const float* __restrict__ K,
    const float* __restrict__ b, const float* __restrict__ G,
    uint4* __restrict__ wsE, uint4* __restrict__ wsO,
    float2* __restrict__ aux) {
  const int t = threadIdx.x;
  const int lane = t & 63;
  const int W = blockIdx.x * 4 + (t >> 6);  // wave id 0..8191
  const int row = W >> 1, h = W & 1;

  const size_t base = (size_t)row * 1024 + h * 512 + lane;
  f4_t v[8];
#pragma unroll
  for (int s = 0; s < 8; ++s) v[s] = adj4[base + s * 64];

  unsigned word = 0;
#pragma unroll
  for (int s = 0; s < 8; ++s) {
    const unsigned nib =
        (v[s].x != 0.f ? 1u : 0u) | (v[s].y != 0.f ? 2u : 0u) |
        (v[s].z != 0.f ? 4u : 0u) | (v[s].w != 0.f ? 8u : 0u);
    word |= nib << (4 * s);
  }
  words[row * 128 + h * 64 + lane] = word;

  // ---- embedded prep (4 blocks x 256 thr = 1024 col-groups) ----
  if (blockIdx.x < 4) {
    const int g = blockIdx.x * 256 + t;  // 0..1023
    const int j0 = 4 * g;
    const float4 x1v = *(const float4*)(x + j0);
    const float4 x2v = *(const float4*)(x + NN + j0);
    const float4 xiA = *(const float4*)(x + 2 * NN + 2 * j0);
    const float4 xiB = *(const float4*)(x + 2 * NN + 2 * j0 + 4);
    const float4 bv0 = *(const float4*)(b + 2 * j0);
    const float4 bv1 = *(const float4*)(b + 2 * j0 + 4);
    const float4 gv0 = *(const float4*)(G + 2 * j0);
    const float4 gv1 = *(const float4*)(G + 2 * j0 + 4);
    const float x1s[4] = {x1v.x, x1v.y, x1v.z, x1v.w};
    const float x2s[4] = {x2v.x, x2v.y, x2v.z, x2v.w};
    const float xis[8] = {xiA.x, xiA.y, xiA.z, xiA.w,
                          xiB.x, xiB.y, xiB.z, xiB.w};
    const float bs[8]  = {bv0.x, bv0.y, bv0.z, bv0.w,
                          bv1.x, bv1.y, bv1.z, bv1.w};
    const float gs[8]  = {gv0.x, gv0.y, gv0.z, gv0.w,
                          gv1.x, gv1.y, gv1.z, gv1.w};
    float cf[4], sf[4], vf[4];
#pragma unroll
    for (int c = 0; c < 4; ++c) {
      const float4 Kv = *(const float4*)(K + 4 * (j0 + c));
      const float M0 = tanhf(fmaf(Kv.x, xis[2 * c], fmaf(Kv.y, xis[2 * c + 1], bs[2 * c])));
      const float M1 = tanhf(fmaf(Kv.z, xis[2 * c], fmaf(Kv.w, xis[2 * c + 1], bs[2 * c + 1])));
      const float d0 = Kv.x * M0 + Kv.z * M1;
      const float d1 = Kv.y * M0 + Kv.w * M1;
      vf[c] = gs[2 * c] * d0 + gs[2 * c + 1] * d1;
      cf[c] = cosf(x1s[c]);
      sf[c] = sinf(x1s[c]);
      aux[j0 + c] = make_float2(d0, d1);
    }
    wsE[g] = make_uint4(pk2rn_u(cf[0], cf[1]), pk2rn_u(sf[0], sf[1]),
                        pk2rn_u(x2s[0], x2s[1]), pk2rn_u(vf[0], vf[1]));
    wsO[g] = make_uint4(pk2rn_u(cf[2], cf[3]), pk2rn_u(sf[2], sf[3]),
                        pk2rn_u(x2s[2], x2s[3]), pk2rn_u(vf[2], vf[3]));
  }
}

// ---- main: wave-per-row; adjacency = 2 uint32/lane; deg = popcount ----
__global__ __launch_bounds__(512, 4) void k_main(
    const float* __restrict__ x, const unsigned* __restrict__ words,
    const float* __restrict__ G, const uint4* __restrict__ wsE,
    const uint4* __restrict__ wsO, const float2* __restrict__ aux,
    float* __restrict__ out) {
  const int t = threadIdx.x;
  const int lane = t & 63, w = t >> 6;
  const int row = blockIdx.x * ROWS + w;

  __shared__ uint4 tabE[NN / 4];  // 16 KB
  __shared__ uint4 tabO[NN / 4];  // 16 KB
  __shared__ float gdeg[ROWS];

  const unsigned w0 = words[row * 128 + lane];
  const unsigned w1 = words[row * 128 + 64 + lane];

  tabE[t] = wsE[t];
  tabE[t + 512] = wsE[t + 512];
  tabO[t] = wsO[t];
  tabO[t + 512] = wsO[t + 512];
  __syncthreads();

  float a0 = 0.f, a1 = 0.f, a2 = 0.f, a3 = 0.f, a4 = 0.f, a5 = 0.f;

#pragma unroll
  for (int half = 0; half < 2; ++half) {
    const unsigned wh = half ? w1 : w0;
#pragma unroll
    for (int j = 0; j < 8; ++j) {
      const unsigned nib = (wh >> (4 * j)) & 15u;
      const int g = half * 512 + j * 64 + lane;
      const uint4 qE = tabE[g];
      const uint4 qO = tabO[g];
      // exact 0/1 f16 pairs from the nibble
      const h2_t hA = bch2(((nib & 1u) ? 0x3C00u : 0u) |
                           ((nib & 2u) ? 0x3C000000u : 0u));
      const h2_t hB = bch2(((nib & 4u) ? 0x3C00u : 0u) |
                           ((nib & 8u) ? 0x3C000000u : 0u));
      {
        const h2_t cc = bch2(qE.x), ss = bch2(qE.y), xx = bch2(qE.z), vv = bch2(qE.w);
        const h2_t tx = hA * xx;
        a0 = fdot2(hA, cc, a0);
        a1 = fdot2(hA, ss, a1);
        a2 = fdot2(tx, cc, a2);
        a3 = fdot2(tx, ss, a3);
        a4 = fdot2(hA, vv, a4);
        a5 = fdot2(hA, xx, a5);
      }
      {
        const h2_t cc = bch2(qO.x), ss = bch2(qO.y), xx = bch2(qO.z), vv = bch2(qO.w);
        const h2_t tx = hB * xx;
        a0 = fdot2(hB, cc, a0);
        a1 = fdot2(hB, ss, a1);
        a2 = fdot2(tx, cc, a2);
        a3 = fdot2(tx, ss, a3);
        a4 = fdot2(hB, vv, a4);
        a5 = fdot2(hB, xx, a5);
      }
    }
  }

  float S[7] = {a0, a1, a2, a3, a4, a5,
                (float)(__builtin_popcount(w0) + __builtin_popcount(w1))};
#pragma unroll
  for (int j = 0; j < 7; ++j) {
    float v = S[j];
    v += __shfl_xor(v, 1);
    v += __shfl_xor(v, 2);
    v += __shfl_xor(v, 4);
    v += __shfl_xor(v, 8);
    v += __shfl_xor(v, 16);
    v += __shfl_xor(v, 32);
    S[j] = v;
  }

  float d0 = 0.f, d1 = 0.f, G0 = 0.f, G1 = 0.f;
  if (lane == 0) {
    const int i = row;
    const float x1i = x[i];
    const float x2i = x[NN + i];
    const float2 au = aux[i];
    d0 = au.x; d1 = au.y;
    G0 = G[2 * i]; G1 = G[2 * i + 1];
    const float ci = cosf(x1i), si = sinf(x1i);

    const float sint = ci * x2i * S[0] + si * x2i * S[1] - ci * S[2] - si * S[3];
    out[i] = x2i;
    out[NN + i] = (KCOUPLING / (float)NN) * (-S[4]) * sint;

    const float sw = (G0 * G0 + G1 * G1) * (1.0f / ((float)NN * (float)NN));
    gdeg[w] = sw * S[6] * S[6];
  }
  __syncthreads();
  if (lane == 0) {
    float gp = 0.0f;
#pragma unroll
    for (int r = 0; r < ROWS; ++r) gp += gdeg[r];
    const float gamma = 0.85f * gp * (1.0f / (float)ROWS);
    const int i = row;
    out[2 * NN + 2 * i + 0] = -d1 - gamma * d0 + (G0 * (1.0f / NN)) * S[5];
    out[2 * NN + 2 * i + 1] =  d0 - gamma * d1 + (G1 * (1.0f / NN)) * S[5];
  }
}

extern "C" void kernel_launch(void* const* d_in, const int* in_sizes, int n_in,
                              void* d_out, int out_size, void* d_ws,
                              size_t ws_size, hipStream_t stream) {
  (void)in_sizes; (void)n_in; (void)out_size; (void)ws_size;
  const float* x    = (const float*)d_in[1];
  const f4_t*  adj4 = (const f4_t*)d_in[2];
  const float* K    = (const float*)d_in[3];
  const float* b    = (const float*)d_in[4];
  const float* G    = (const float*)d_in[5];
  float* out = (float*)d_out;

  char* ws = (char*)d_ws;
  uint4*    wsE   = (uint4*)(ws);            // 16 KB
  uint4*    wsO   = (uint4*)(ws + 16384);    // 16 KB
  float2*   aux   = (float2*)(ws + 32768);   // 32 KB
  unsigned* words = (unsigned*)(ws + 65536); // 2 MB

  k_pack<<<2048, 256, 0, stream>>>(adj4, words, x, K, b, G, wsE, wsO, aux);
  k_main<<<512, 512, 0, stream>>>(x, words, G, wsE, wsO, aux, out);
}

// Round 14
// 21.591 us; speedup vs baseline: 1.0757x; 1.0757x over previous
//
#include <hip/hip_runtime.h>
#include <hip/hip_fp16.h>

// Kuramoto closed-loop — ONE kernel, no workspace.
//
//  s_int[j] = cj*x2j*(A c)j + sj*x2j*(A s)j - cj*(A (c*x2))j - sj*(A (s*x2))j
//  u        = -(A v);  gterm = G2d/n * (A x2)
//  gamma   ~= 0.85 * mean_{8 rows of block}(sw_i * deg_i^2)  (Rayleigh sample)
//
// Lessons ledger:
//  r1/r3/r4: register tables spill -> WRITE_SIZE is the spill alarm.
//  r5:  prefetch distance must match buffer count.
//  r6:  split tabE/tabO -> conflict-free b128 (655K -> 0).
//  r7:  builtins return __fp16 vectors -> decltype the builtin.
//  r8:  redundant SLOW (libm) table build cost ~2.5us net -> prep split.
//  r9-r13: 20-25us across 5 structures; read stream pinned at ~4 TB/s
//       (= ~0.5 TB/s ingress x 8 XCDs). Floor = 64MB/4TB/s = 16.3us.
//       r12 (nt loads, prep split) = 20.5 best -> ~4us is launch/prep.
//  r14(this): single kernel. Table build per block with FAST transcendentals
//       (__expf tanh, __sinf/__cosf: ~40 VALU/col vs libm ~100), hidden under
//       the nt-load stall (VALUBusy was 20%). Build reads are L2-local (not
//       ingress). aux for the block's 8 rows captured in LDS during build.

#define NN 4096
#define KCOUPLING 3.0f
#define ROWS 8
#define NBLK (NN / ROWS)  // 512 blocks x 512 thr

typedef decltype(__builtin_amdgcn_cvt_pkrtz(0.0f, 0.0f)) h2_t;  // __fp16 x2
typedef float f4_t __attribute__((ext_vector_type(4)));

__device__ __forceinline__ unsigned pk2rn_u(float a, float b) {  // RN table
  __half2 h = __floats2half2_rn(a, b);
  return *reinterpret_cast<unsigned*>(&h);
}
__device__ __forceinline__ float fdot2(h2_t a, h2_t b, float c) {
#if __has_builtin(__builtin_amdgcn_fdot2)
  return __builtin_amdgcn_fdot2(a, b, c, false);
#else
  return fmaf((float)a.x, (float)b.x, fmaf((float)a.y, (float)b.y, c));
#endif
}
__device__ __forceinline__ h2_t bch2(unsigned u) {
  union { unsigned u; h2_t h; } x; x.u = u; return x.h;
}
__device__ __forceinline__ f4_t ntload4(const f4_t* p) {
  return __builtin_nontemporal_load(p);
}
__device__ __forceinline__ float ftanh(float x) {
  // 1 - 2/(e^{2x}+1); e overflow -> +1, underflow -> -1 (correct saturation)
  const float e = __expf(2.0f * x);
  return 1.0f - 2.0f / (e + 1.0f);
}

__global__ __launch_bounds__(512, 4) void k_fused(
    const float* __restrict__ x, const f4_t* __restrict__ adj4,
    const float* __restrict__ K, const float* __restrict__ b,
    const float* __restrict__ G, float* __restrict__ out) {
  const int t = threadIdx.x;
  const int lane = t & 63, w = t >> 6;
  const int blk = blockIdx.x;
  const int row = blk * ROWS + w;

  __shared__ uint4 tabE[NN / 4];   // 16 KB
  __shared__ uint4 tabO[NN / 4];   // 16 KB
  __shared__ float gdeg[ROWS];
  __shared__ float2 auxl[ROWS];    // (d0,d1) for this block's 8 rows

  const int base = row * 1024 + lane;  // f4 units; row stride 1024 f4

  // half 0 in flight before/during the table build
  f4_t A[8], B[8];
#pragma unroll
  for (int j = 0; j < 8; ++j) A[j] = ntload4(adj4 + base + j * 64);

  // ---- build table (per block, fast-math, hidden under load stall) ----
#pragma unroll
  for (int gidx = 0; gidx < 2; ++gidx) {
    const int g = t + 512 * gidx;  // col group 0..1023, cols 4g..4g+3
    const int j0 = 4 * g;
    const float4 x1v = *(const float4*)(x + j0);
    const float4 x2v = *(const float4*)(x + NN + j0);
    const float4 xiA = *(const float4*)(x + 2 * NN + 2 * j0);
    const float4 xiB = *(const float4*)(x + 2 * NN + 2 * j0 + 4);
    const float4 bv0 = *(const float4*)(b + 2 * j0);
    const float4 bv1 = *(const float4*)(b + 2 * j0 + 4);
    const float4 gv0 = *(const float4*)(G + 2 * j0);
    const float4 gv1 = *(const float4*)(G + 2 * j0 + 4);
    const float x1s[4] = {x1v.x, x1v.y, x1v.z, x1v.w};
    const float x2s[4] = {x2v.x, x2v.y, x2v.z, x2v.w};
    const float xis[8] = {xiA.x, xiA.y, xiA.z, xiA.w,
                          xiB.x, xiB.y, xiB.z, xiB.w};
    const float bs[8]  = {bv0.x, bv0.y, bv0.z, bv0.w,
                          bv1.x, bv1.y, bv1.z, bv1.w};
    const float gs[8]  = {gv0.x, gv0.y, gv0.z, gv0.w,
                          gv1.x, gv1.y, gv1.z, gv1.w};
    float cf[4], sf[4], vf[4];
#pragma unroll
    for (int c = 0; c < 4; ++c) {
      const float4 Kv = *(const float4*)(K + 4 * (j0 + c));
      const float M0 = ftanh(fmaf(Kv.x, xis[2 * c], fmaf(Kv.y, xis[2 * c + 1], bs[2 * c])));
      const float M1 = ftanh(fmaf(Kv.z, xis[2 * c], fmaf(Kv.w, xis[2 * c + 1], bs[2 * c + 1])));
      const float d0 = Kv.x * M0 + Kv.z * M1;
      const float d1 = Kv.y * M0 + Kv.w * M1;
      vf[c] = gs[2 * c] * d0 + gs[2 * c + 1] * d1;
      cf[c] = __cosf(x1s[c]);
      sf[c] = __sinf(x1s[c]);
      if ((g >> 1) == blk) auxl[4 * (g & 1) + c] = make_float2(d0, d1);
    }
    tabE[g] = make_uint4(pk2rn_u(cf[0], cf[1]), pk2rn_u(sf[0], sf[1]),
                         pk2rn_u(x2s[0], x2s[1]), pk2rn_u(vf[0], vf[1]));
    tabO[g] = make_uint4(pk2rn_u(cf[2], cf[3]), pk2rn_u(sf[2], sf[3]),
                         pk2rn_u(x2s[2], x2s[3]), pk2rn_u(vf[2], vf[3]));
  }
  __syncthreads();

  // half 1 in flight while half 0 computes
#pragma unroll
  for (int j = 0; j < 8; ++j) B[j] = ntload4(adj4 + base + (8 + j) * 64);

  float a0 = 0.f, a1 = 0.f, a2 = 0.f, a3 = 0.f, a4 = 0.f, a5 = 0.f, a6 = 0.f;
  const h2_t ONE = bch2(pk2rn_u(1.0f, 1.0f));

#pragma unroll
  for (int half = 0; half < 2; ++half) {
#pragma unroll
    for (int j = 0; j < 8; ++j) {
      const f4_t av4 = half ? B[j] : A[j];
      const int g = (half * 8 + j) * 64 + lane;
      const uint4 qE = tabE[g];
      const uint4 qO = tabO[g];
      const h2_t hA = __builtin_amdgcn_cvt_pkrtz(av4.x, av4.y);  // 0/1 exact
      const h2_t hB = __builtin_amdgcn_cvt_pkrtz(av4.z, av4.w);
      {
        const h2_t cc = bch2(qE.x), ss = bch2(qE.y), xx = bch2(qE.z), vv = bch2(qE.w);
        const h2_t tx = hA * xx;
        a0 = fdot2(hA, cc, a0);
        a1 = fdot2(hA, ss, a1);
        a2 = fdot2(tx, cc, a2);
        a3 = fdot2(tx, ss, a3);
        a4 = fdot2(hA, vv, a4);
        a5 = fdot2(hA, xx, a5);
        a6 = fdot2(hA, ONE, a6);
      }
      {
        const h2_t cc = bch2(qO.x), ss = bch2(qO.y), xx = bch2(qO.z), vv = bch2(qO.w);
        const h2_t tx = hB * xx;
        a0 = fdot2(hB, cc, a0);
        a1 = fdot2(hB, ss, a1);
        a2 = fdot2(tx, cc, a2);
        a3 = fdot2(tx, ss, a3);
        a4 = fdot2(hB, vv, a4);
        a5 = fdot2(hB, xx, a5);
        a6 = fdot2(hB, ONE, a6);
      }
    }
  }

  float S[7] = {a0, a1, a2, a3, a4, a5, a6};
#pragma unroll
  for (int j = 0; j < 7; ++j) {
    float v = S[j];
    v += __shfl_xor(v, 1);
    v += __shfl_xor(v, 2);
    v += __shfl_xor(v, 4);
    v += __shfl_xor(v, 8);
    v += __shfl_xor(v, 16);
    v += __shfl_xor(v, 32);
    S[j] = v;
  }

  float d0 = 0.f, d1 = 0.f, G0 = 0.f, G1 = 0.f;
  if (lane == 0) {
    const int i = row;
    const float x1i = x[i];
    const float x2i = x[NN + i];
    const float2 au = auxl[w];
    d0 = au.x; d1 = au.y;
    G0 = G[2 * i]; G1 = G[2 * i + 1];
    const float ci = __cosf(x1i), si = __sinf(x1i);

    const float sint = ci * x2i * S[0] + si * x2i * S[1] - ci * S[2] - si * S[3];
    out[i] = x2i;
    out[NN + i] = (KCOUPLING / (float)NN) * (-S[4]) * sint;

    const float sw = (G0 * G0 + G1 * G1) * (1.0f / ((float)NN * (float)NN));
    gdeg[w] = sw * S[6] * S[6];
  }
  __syncthreads();
  if (lane == 0) {
    float gp = 0.0f;
#pragma unroll
    for (int r = 0; r < ROWS; ++r) gp += gdeg[r];
    const float gamma = 0.85f * gp * (1.0f / (float)ROWS);
    const int i = row;
    out[2 * NN + 2 * i + 0] = -d1 - gamma * d0 + (G0 * (1.0f / NN)) * S[5];
    out[2 * NN + 2 * i + 1] =  d0 - gamma * d1 + (G1 * (1.0f / NN)) * S[5];
  }
}

extern "C" void kernel_launch(void* const* d_in, const int* in_sizes, int n_in,
                              void* d_out, int out_size, void* d_ws,
                              size_t ws_size, hipStream_t stream) {
  (void)in_sizes; (void)n_in; (void)out_size; (void)d_ws; (void)ws_size;
  const float* x    = (const float*)d_in[1];
  const f4_t*  adj4 = (const f4_t*)d_in[2];
  const float* K    = (const float*)d_in[3];
  const float* b    = (const float*)d_in[4];
  const float* G    = (const float*)d_in[5];
  float* out = (float*)d_out;

  k_fused<<<NBLK, 512, 0, stream>>>(x, adj4, K, b, G, out);
}

// Round 15
// 20.956 us; speedup vs baseline: 1.1083x; 1.0303x over previous
//
#include <hip/hip_runtime.h>

// Kuramoto closed-loop — symmetric-tile sweep + finalize.
//
//  S[i] = Sum_j a_ij * {c,s,cx,sx,v,x2,1}_j  (7 sums per row), then
//  sint/u/gterm/gamma as before. adj symmetric -> tile (I,J), I<=J, read ONCE
//  serves rows I (P: row sums via 2KB bit-transposed tile in LDS) AND rows J
//  (Q: column sums, lane-local). Traffic 64MB -> 33.8MB. part[slot][row][8]
//  written exactly once per slot (P->slot J, Q->slot I; diagonal P only).
//
// Lessons ledger:
//  r1/r3/r4: register tables spill -> WRITE_SIZE is the spill alarm.
//  r5:  prefetch distance must match buffer count.
//  r6:  LDS layouts: broadcast or split-array for conflict-free reads.
//  r7:  builtins return __fp16 vectors -> decltype the builtin.
//  r8:  build shared tables once, not per block.
//  r9-r14: ~4 TB/s L3/fabric read wall; 5 engines all pinned 20-25us.
//       r12 best 20.5 = 16.3us stream + ~4us overhead. Only lever: fewer bytes.
//  r15(this): symmetry halves bytes. Q = lane-local col sums (f32 FMA);
//       P via exact bit-pack transpose in LDS; all tab reads broadcast;
//       f32 everywhere (absmax should drop); no atomics.

#define NN 4096
#define KCOUPLING 3.0f
#define TS 128
#define NT (NN / TS)                 // 32
#define NTILES (NT * (NT + 1) / 2)   // 528

typedef float f2_t __attribute__((ext_vector_type(2)));

__device__ __forceinline__ float ftanh(float x) {
  const float e = __expf(2.0f * x);
  return 1.0f - 2.0f / (e + 1.0f);  // saturates correctly at +-1
}
__device__ __forceinline__ f2_t ntload2(const f2_t* p) {
  return __builtin_nontemporal_load(p);
}

__device__ __forceinline__ void build_node(
    const float* __restrict__ x, const float* __restrict__ K,
    const float* __restrict__ b, const float* __restrict__ G,
    int n, float* row8) {
  const float x1 = x[n];
  const float x2 = x[NN + n];
  const float xi0 = x[2 * NN + 2 * n];
  const float xi1 = x[2 * NN + 2 * n + 1];
  const float4 Kv = *(const float4*)(K + 4 * n);
  const float b0 = b[2 * n], b1 = b[2 * n + 1];
  const float G0 = G[2 * n], G1 = G[2 * n + 1];
  const float M0 = ftanh(fmaf(Kv.x, xi0, fmaf(Kv.y, xi1, b0)));
  const float M1 = ftanh(fmaf(Kv.z, xi0, fmaf(Kv.w, xi1, b1)));
  const float d0 = Kv.x * M0 + Kv.z * M1;
  const float d1 = Kv.y * M0 + Kv.w * M1;
  const float c = __cosf(x1), s = __sinf(x1);
  row8[0] = c; row8[1] = s; row8[2] = c * x2; row8[3] = s * x2;
  row8[4] = G0 * d0 + G1 * d1; row8[5] = x2; row8[6] = 0.f; row8[7] = 0.f;
}

__global__ __launch_bounds__(256, 4) void k_tiles(
    const float* __restrict__ x, const float* __restrict__ adj,
    const float* __restrict__ K, const float* __restrict__ b,
    const float* __restrict__ G, float* __restrict__ part) {
  // decode upper-triangular tile (I,J), I<=J
  int k = blockIdx.x, I = 0;
  while (k >= NT - I) { k -= NT - I; ++I; }
  const int J = I + k;
  const int RI = I * TS, CJ = J * TS;

  const int t = threadIdx.x;
  const int r0 = t >> 6;         // wave index = row phase 0..3 (rows 4s+r0)
  const int c0 = 2 * (t & 63);   // col pair owned in Q-sweep

  __shared__ float tabI[TS][8];     // 4 KB  {c,s,cx,sx,v,x2,0,0} rows I
  __shared__ float tabJ[TS][8];     // 4 KB  cols J
  __shared__ unsigned pkT[TS][4];   // 2 KB  pkT[col][r&3] bit (r>>2) = a[r][col]
  __shared__ float Qp[4][TS][8];    // 16 KB col partials per row-phase
  __shared__ float Pp[2][TS][8];    // 8 KB  row partials per col-half

  const f2_t* adj2 = (const f2_t*)adj;
  const int base2 = (RI + r0) * (NN / 2) + (CJ >> 1) + (t & 63);

  // prefetch batch 0 (8 of 32 row-steps) before table build
  f2_t A[2][8];
#pragma unroll
  for (int s = 0; s < 8; ++s) A[0][s] = ntload2(adj2 + base2 + (4 * s) * (NN / 2));

  {
    float row8[8];
    if (t < TS) {
      build_node(x, K, b, G, RI + t, row8);
#pragma unroll
      for (int q = 0; q < 8; ++q) tabI[t][q] = row8[q];
    } else {
      build_node(x, K, b, G, CJ + (t - TS), row8);
#pragma unroll
      for (int q = 0; q < 8; ++q) tabJ[t - TS][q] = row8[q];
    }
  }
  __syncthreads();

  // ---- Q-sweep: lane-local column sums over rows 4s+r0; also bit-pack ----
  float q0[7] = {0, 0, 0, 0, 0, 0, 0}, q1[7] = {0, 0, 0, 0, 0, 0, 0};
  unsigned w0 = 0, w1 = 0;

#pragma unroll
  for (int batch = 0; batch < 4; ++batch) {
    if (batch + 1 < 4) {
#pragma unroll
      for (int s = 0; s < 8; ++s)
        A[(batch + 1) & 1][s] =
            ntload2(adj2 + base2 + (4 * ((batch + 1) * 8 + s)) * (NN / 2));
    }
#pragma unroll
    for (int s2 = 0; s2 < 8; ++s2) {
      const int s = batch * 8 + s2;
      const f2_t a = A[batch & 1][s2];
      const int r = 4 * s + r0;
      const float4 t4 = *(const float4*)&tabI[r][0];  // broadcast (uniform r)
      const f2_t t2 = *(const f2_t*)&tabI[r][4];
      w0 |= (a.x != 0.f ? 1u : 0u) << s;
      w1 |= (a.y != 0.f ? 1u : 0u) << s;
      q0[0] = fmaf(a.x, t4.x, q0[0]); q1[0] = fmaf(a.y, t4.x, q1[0]);
      q0[1] = fmaf(a.x, t4.y, q0[1]); q1[1] = fmaf(a.y, t4.y, q1[1]);
      q0[2] = fmaf(a.x, t4.z, q0[2]); q1[2] = fmaf(a.y, t4.z, q1[2]);
      q0[3] = fmaf(a.x, t4.w, q0[3]); q1[3] = fmaf(a.y, t4.w, q1[3]);
      q0[4] = fmaf(a.x, t2.x, q0[4]); q1[4] = fmaf(a.y, t2.x, q1[4]);
      q0[5] = fmaf(a.x, t2.y, q0[5]); q1[5] = fmaf(a.y, t2.y, q1[5]);
      q0[6] += a.x;                   q1[6] += a.y;
    }
  }
  pkT[c0][r0] = w0;
  pkT[c0 + 1][r0] = w1;
#pragma unroll
  for (int q = 0; q < 7; ++q) {
    Qp[r0][c0][q] = q0[q];
    Qp[r0][c0 + 1][q] = q1[q];
  }
  __syncthreads();

  // ---- P-sweep: row sums from bit-transposed tile (exact 0/1 bits) ----
  {
    const int r = t & (TS - 1), h = t >> 7;  // row, col-half
    const int rb = r & 3, rs = r >> 2;
    float p[7] = {0, 0, 0, 0, 0, 0, 0};
#pragma unroll
    for (int jj = 0; jj < 64; ++jj) {
      const int j = h * 64 + jj;                   // uniform j per wave
      const unsigned word = pkT[j][rb];            // 4-addr broadcast
      const float av = (float)((word >> rs) & 1u);
      const float4 t4 = *(const float4*)&tabJ[j][0];  // full broadcast
      const f2_t t2 = *(const f2_t*)&tabJ[j][4];
      p[0] = fmaf(av, t4.x, p[0]);
      p[1] = fmaf(av, t4.y, p[1]);
      p[2] = fmaf(av, t4.z, p[2]);
      p[3] = fmaf(av, t4.w, p[3]);
      p[4] = fmaf(av, t2.x, p[4]);
      p[5] = fmaf(av, t2.y, p[5]);
      p[6] += av;
    }
#pragma unroll
    for (int q = 0; q < 7; ++q) Pp[h][r][q] = p[q];
  }
  __syncthreads();

  // ---- writers: P -> slot J rows RI+r ; Q -> slot I rows CJ+c (I!=J) ----
  if (t < TS) {
    const int r = t;
    float4 lo, hi;
    lo.x = Pp[0][r][0] + Pp[1][r][0];
    lo.y = Pp[0][r][1] + Pp[1][r][1];
    lo.z = Pp[0][r][2] + Pp[1][r][2];
    lo.w = Pp[0][r][3] + Pp[1][r][3];
    hi.x = Pp[0][r][4] + Pp[1][r][4];
    hi.y = Pp[0][r][5] + Pp[1][r][5];
    hi.z = Pp[0][r][6] + Pp[1][r][6];
    hi.w = 0.f;
    float* dst = part + ((size_t)J * NN + RI + r) * 8;
    *(float4*)dst = lo;
    *(float4*)(dst + 4) = hi;
  } else if (I != J) {
    const int c = t - TS;
    float4 lo, hi;
    lo.x = Qp[0][c][0] + Qp[1][c][0] + Qp[2][c][0] + Qp[3][c][0];
    lo.y = Qp[0][c][1] + Qp[1][c][1] + Qp[2][c][1] + Qp[3][c][1];
    lo.z = Qp[0][c][2] + Qp[1][c][2] + Qp[2][c][2] + Qp[3][c][2];
    lo.w = Qp[0][c][3] + Qp[1][c][3] + Qp[2][c][3] + Qp[3][c][3];
    hi.x = Qp[0][c][4] + Qp[1][c][4] + Qp[2][c][4] + Qp[3][c][4];
    hi.y = Qp[0][c][5] + Qp[1][c][5] + Qp[2][c][5] + Qp[3][c][5];
    hi.z = Qp[0][c][6] + Qp[1][c][6] + Qp[2][c][6] + Qp[3][c][6];
    hi.w = 0.f;
    float* dst = part + ((size_t)I * NN + CJ + c) * 8;
    *(float4*)dst = lo;
    *(float4*)(dst + 4) = hi;
  }
}

// ---- finalize: sum 32 slots per row, apply output math (all f32) ----
__global__ __launch_bounds__(64) void k_final(
    const float* __restrict__ x, const float* __restrict__ K,
    const float* __restrict__ b, const float* __restrict__ G,
    const float* __restrict__ part, float* __restrict__ out) {
  const int i = blockIdx.x * 64 + threadIdx.x;
  float S[7] = {0, 0, 0, 0, 0, 0, 0};
#pragma unroll
  for (int s = 0; s < NT; ++s) {
    const float* p = part + ((size_t)s * NN + i) * 8;
    const float4 lo = *(const float4*)p;
    const float4 hi = *(const float4*)(p + 4);
    S[0] += lo.x; S[1] += lo.y; S[2] += lo.z; S[3] += lo.w;
    S[4] += hi.x; S[5] += hi.y; S[6] += hi.z;
  }

  const float x1 = x[i];
  const float x2 = x[NN + i];
  const float xi0 = x[2 * NN + 2 * i], xi1 = x[2 * NN + 2 * i + 1];
  const float4 Kv = *(const float4*)(K + 4 * i);
  const float b0 = b[2 * i], b1 = b[2 * i + 1];
  const float G0 = G[2 * i], G1 = G[2 * i + 1];
  const float M0 = ftanh(fmaf(Kv.x, xi0, fmaf(Kv.y, xi1, b0)));
  const float M1 = ftanh(fmaf(Kv.z, xi0, fmaf(Kv.w, xi1, b1)));
  const float d0 = Kv.x * M0 + Kv.z * M1;
  const float d1 = Kv.y * M0 + Kv.w * M1;
  const float ci = __cosf(x1), si = __sinf(x1);

  const float sint = ci * x2 * S[0] + si * x2 * S[1] - ci * S[2] - si * S[3];
  out[i] = x2;
  out[NN + i] = (KCOUPLING / (float)NN) * (-S[4]) * sint;

  // gamma Rayleigh sample over this wave's 64 rows
  const float sw = (G0 * G0 + G1 * G1) * (1.0f / ((float)NN * (float)NN));
  float g = sw * S[6] * S[6];
  g += __shfl_xor(g, 1);
  g += __shfl_xor(g, 2);
  g += __shfl_xor(g, 4);
  g += __shfl_xor(g, 8);
  g += __shfl_xor(g, 16);
  g += __shfl_xor(g, 32);
  const float gamma = 0.85f * g * (1.0f / 64.0f);

  out[2 * NN + 2 * i + 0] = -d1 - gamma * d0 + (G0 * (1.0f / NN)) * S[5];
  out[2 * NN + 2 * i + 1] =  d0 - gamma * d1 + (G1 * (1.0f / NN)) * S[5];
}

extern "C" void kernel_launch(void* const* d_in, const int* in_sizes, int n_in,
                              void* d_out, int out_size, void* d_ws,
                              size_t ws_size, hipStream_t stream) {
  (void)in_sizes; (void)n_in; (void)out_size; (void)ws_size;
  const float* x   = (const float*)d_in[1];
  const float* adj = (const float*)d_in[2];
  const float* K   = (const float*)d_in[3];
  const float* b   = (const float*)d_in[4];
  const float* G   = (const float*)d_in[5];
  float* out = (float*)d_out;

  float* part = (float*)d_ws;  // 32 * 4096 * 8 * 4 B = 4 MiB

  k_tiles<<<NTILES, 256, 0, stream>>>(x, adj, K, b, G, part);
  k_final<<<NN / 64, 64, 0, stream>>>(x, K, b, G, part, out);
}